// Round 2
// baseline (258.186 us; speedup 1.0000x reference)
//
#include <hip/hip_runtime.h>

// DTCWT forward, J=3, B=4 C=64 H=W=256, fp32.
// Level 1: rowfilter(h0o/h1o, odd taps, symmetric pad) -> colfilter -> q2c
// Level 2+: rowdfilt/coldfilt (10-tap, stride 2, phase-split ha/hb) -> q2c
// XLA conv = cross-correlation (no flip). Reflection: half-sample symmetric.
// Downsampled filters: output pair u reads input at refl(4u + 2k - 8) (even
// phase) / refl(4u + 2k - 7) (odd phase); highpass swaps the two phases.

#define NIMG 256          // B*C
#define INV_SQRT2 0.7071067811865476f

__device__ __forceinline__ int refl(int i, int n) {
    // single reflection is sufficient for all index ranges in this problem
    return i < 0 ? (-i - 1) : (i >= n ? (2 * n - 1 - i) : i);
}

// ---------------- Level 1 ----------------
__global__ __launch_bounds__(256, 2)
void dtcwt_l1(const float* __restrict__ x,
              const float* __restrict__ h0o,
              const float* __restrict__ h1o,
              float* __restrict__ ll,     // (NIMG,256,256) ws
              float* __restrict__ yh)     // (NIMG,6,128,128,2)
{
    __shared__ float xs[22][256];
    __shared__ float slo[22][256];
    __shared__ float shi[22][256];
    __shared__ float stg[3][2][256];   // lh, hl, hh rows (pair)

    const int img = blockIdx.y;
    const int r0  = blockIdx.x * 16;
    const int tid = threadIdx.x;

    float f0[5], f1[7];
#pragma unroll
    for (int k = 0; k < 5; ++k) f0[k] = h0o[k];
#pragma unroll
    for (int k = 0; k < 7; ++k) f1[k] = h1o[k];

    const float* xim = x + (size_t)img * 65536;

    // load 22 rows (halo +-3, row-reflected)
    for (int idx = tid; idx < 22 * 256; idx += 256) {
        int lr = idx >> 8, c = idx & 255;
        int gr = refl(r0 - 3 + lr, 256);
        xs[lr][c] = xim[gr * 256 + c];
    }
    __syncthreads();

    // row filter: lo = x*h0o (m=2), hi = x*h1o (m=3); out[c] = sum_k x[refl(c-m+k)]h[k]
    for (int idx = tid; idx < 22 * 256; idx += 256) {
        int lr = idx >> 8, c = idx & 255;
        float alo = 0.f, ahi = 0.f;
#pragma unroll
        for (int k = 0; k < 5; ++k) {
            int cc = refl(c - 2 + k, 256);
            alo += xs[lr][cc] * f0[k];
        }
#pragma unroll
        for (int k = 0; k < 7; ++k) {
            int cc = refl(c - 3 + k, 256);
            ahi += xs[lr][cc] * f1[k];
        }
        slo[lr][c] = alo;
        shi[lr][c] = ahi;
    }
    __syncthreads();

    float* llim = ll + (size_t)img * 65536;
    float* yim  = yh + (size_t)img * (6 * 128 * 128 * 2);

    for (int ii = 0; ii < 8; ++ii) {
#pragma unroll
        for (int p = 0; p < 2; ++p) {
            const int c  = tid;
            const int rr = 2 * ii + p;          // local out row in [0,16)
            // col filter; LDS row 0 == global row r0-3
            float vll = 0.f, vlh = 0.f, vhl = 0.f, vhh = 0.f;
#pragma unroll
            for (int k = 0; k < 5; ++k) {       // h0o, m=2 -> lds row rr+1+k
                float a = slo[rr + 1 + k][c], b = shi[rr + 1 + k][c];
                vll += a * f0[k]; vhl += b * f0[k];
            }
#pragma unroll
            for (int k = 0; k < 7; ++k) {       // h1o, m=3 -> lds row rr+k
                float a = slo[rr + k][c], b = shi[rr + k][c];
                vlh += a * f1[k]; vhh += b * f1[k];
            }
            llim[(size_t)(r0 + rr) * 256 + c] = vll;
            stg[0][p][c] = vlh;   // lh
            stg[1][p][c] = vhl;   // hl
            stg[2][p][c] = vhh;   // hh
        }
        __syncthreads();
        if (tid < 128) {
            const int j = tid;
            const int i = (r0 >> 1) + ii;
#pragma unroll
            for (int band = 0; band < 3; ++band) {
                float a  = stg[band][0][2 * j]     * INV_SQRT2;
                float b  = stg[band][0][2 * j + 1] * INV_SQRT2;
                float c2 = stg[band][1][2 * j]     * INV_SQRT2;
                float d  = stg[band][1][2 * j + 1] * INV_SQRT2;
                int o1, o2;
                if (band == 0)      { o1 = 0; o2 = 5; }  // lh -> d15, d165
                else if (band == 1) { o1 = 2; o2 = 3; }  // hl -> d75, d105
                else                { o1 = 1; o2 = 4; }  // hh -> d45, d135
                *(float2*)(yim + ((size_t)(o1 * 128 + i) * 128 + j) * 2) =
                    make_float2(a - d, b + c2);
                *(float2*)(yim + ((size_t)(o2 * 128 + i) * 128 + j) * 2) =
                    make_float2(a + d, b - c2);
            }
        }
        __syncthreads();
    }
}

// ---------------- Levels 2+ ----------------
// Output pair u, even row: sum_k In[refl(4u+2k-8)]*ha[k], odd: refl(4u+2k-7)*hb[k]
// lowpass call (ha=h0b, hb=h0a); highpass call (ha=h1b, hb=h1a) then SWAP:
//   even = h1a @ -7 phase, odd = h1b @ -8 phase.
template <int CI>
__global__ __launch_bounds__(256, 2)
void dtcwt_l2(const float* __restrict__ llin, int R,
              const float* __restrict__ h0a, const float* __restrict__ h0b,
              const float* __restrict__ h1a, const float* __restrict__ h1b,
              float* __restrict__ llout,   // (NIMG, R/2, CI/2)
              float* __restrict__ yh)      // (NIMG, 6, R/4, CI/4, 2)
{
    constexpr int CH2 = CI / 2;
    constexpr int CQ  = CI / 4;
    constexpr int NI  = 4;            // coldfilt pair-indices (u) per block
    constexpr int NR  = 4 * NI + 16;  // staged Y rows [4*i0-8, 4*i0+4*NI+7]

    __shared__ float xs [NR][CI];
    __shared__ float ylo[NR][CH2];
    __shared__ float yhi[NR][CH2];
    __shared__ float stg[3][2 * NI][CH2];

    const int img = blockIdx.y;
    const int i0  = blockIdx.x * NI;
    const int tid = threadIdx.x;

    float fa0[10], fb0[10], fa1[10], fb1[10];
#pragma unroll
    for (int k = 0; k < 10; ++k) {
        fa0[k] = h0a[k]; fb0[k] = h0b[k];
        fa1[k] = h1a[k]; fb1[k] = h1b[k];
    }

    const float* xim = llin + (size_t)img * R * CI;

    // stage input rows refl(4*i0 - 8 + lr), lr in [0, NR)
    for (int idx = tid; idx < NR * CI; idx += 256) {
        int lr = idx / CI, c = idx % CI;
        int gr = refl(4 * i0 - 8 + lr, R);
        xs[lr][c] = xim[gr * CI + c];
    }
    __syncthreads();

    // rowdfilt both trees: out col 2j   <- refl(4j+2k-8) (lo: h0b / hi: h1b@odd)
    //                      out col 2j+1 <- refl(4j+2k-7)
    for (int idx = tid; idx < NR * CH2; idx += 256) {
        int r = idx / CH2, c2 = idx % CH2;
        int j = c2 >> 1, p = c2 & 1;
        float vlo = 0.f, vhi = 0.f;
#pragma unroll
        for (int k = 0; k < 10; ++k) {
            int ca = refl(4 * j + 2 * k - 8, CI);   // even phase
            int cb = refl(4 * j + 2 * k - 7, CI);   // odd phase
            float xa = xs[r][ca], xb = xs[r][cb];
            if (p == 0) { vlo += xa * fb0[k]; vhi += xb * fa1[k]; }
            else        { vlo += xb * fa0[k]; vhi += xa * fb1[k]; }
        }
        ylo[r][c2] = vlo;
        yhi[r][c2] = vhi;
    }
    __syncthreads();

    float* llo = llout + (size_t)img * (R / 2) * CH2;

    // coldfilt all 4 bands; LDS row 0 == Y row 4*i0-8, so
    // global row 4*(i0+ii)+2k-8 -> lds row 4*ii+2k
    for (int idx = tid; idx < 2 * NI * CH2; idx += 256) {
        int rr = idx / CH2, c2 = idx % CH2;
        int ii = rr >> 1, q = rr & 1;
        float vll = 0.f, vlh = 0.f, vhl = 0.f, vhh = 0.f;
#pragma unroll
        for (int k = 0; k < 10; ++k) {
            int ra = 4 * ii + 2 * k;    // even (-8) phase lds row
            int rb = ra + 1;            // odd  (-7) phase
            float lA = ylo[ra][c2], lB = ylo[rb][c2];
            float hA = yhi[ra][c2], hB = yhi[rb][c2];
            if (q == 0) {
                vll += lA * fb0[k]; vlh += lB * fa1[k];
                vhl += hA * fb0[k]; vhh += hB * fa1[k];
            } else {
                vll += lB * fa0[k]; vlh += lA * fb1[k];
                vhl += hB * fa0[k]; vhh += hA * fb1[k];
            }
        }
        llo[(size_t)(2 * i0 + rr) * CH2 + c2] = vll;
        stg[0][rr][c2] = vlh;
        stg[1][rr][c2] = vhl;
        stg[2][rr][c2] = vhh;
    }
    __syncthreads();

    float* yim = yh + (size_t)img * (6 * (R / 4) * CQ * 2);
    const int RQ = R / 4;
    for (int idx = tid; idx < NI * CQ; idx += 256) {
        int il = idx / CQ, j = idx % CQ;
        int i = i0 + il;
#pragma unroll
        for (int band = 0; band < 3; ++band) {
            float a = stg[band][2 * il][2 * j]         * INV_SQRT2;
            float b = stg[band][2 * il][2 * j + 1]     * INV_SQRT2;
            float c = stg[band][2 * il + 1][2 * j]     * INV_SQRT2;
            float d = stg[band][2 * il + 1][2 * j + 1] * INV_SQRT2;
            int o1, o2;
            if (band == 0)      { o1 = 0; o2 = 5; }
            else if (band == 1) { o1 = 2; o2 = 3; }
            else                { o1 = 1; o2 = 4; }
            *(float2*)(yim + ((size_t)(o1 * RQ + i) * CQ + j) * 2) =
                make_float2(a - d, b + c);
            *(float2*)(yim + ((size_t)(o2 * RQ + i) * CQ + j) * 2) =
                make_float2(a + d, b - c);
        }
    }
}

extern "C" void kernel_launch(void* const* d_in, const int* in_sizes, int n_in,
                              void* d_out, int out_size, void* d_ws, size_t ws_size,
                              hipStream_t stream)
{
    const float* x   = (const float*)d_in[0];
    const float* h0o = (const float*)d_in[1];
    const float* h1o = (const float*)d_in[2];
    const float* h0a = (const float*)d_in[3];
    const float* h0b = (const float*)d_in[4];
    const float* h1a = (const float*)d_in[5];
    const float* h1b = (const float*)d_in[6];
    float* out = (float*)d_out;

    float* ll1 = (float*)d_ws;            // 16,777,216 floats (64 MB)
    float* ll2 = ll1 + 16777216;          //  4,194,304 floats (16 MB)

    float* ll3 = out;                     //  1,048,576
    float* yh1 = out + 1048576;           // 50,331,648
    float* yh2 = out + 51380224;          // 12,582,912
    float* yh3 = out + 63963136;          //  3,145,728

    dtcwt_l1<<<dim3(16, 256), 256, 0, stream>>>(x, h0o, h1o, ll1, yh1);
    dtcwt_l2<256><<<dim3(16, 256), 256, 0, stream>>>(ll1, 256, h0a, h0b, h1a, h1b, ll2, yh2);
    dtcwt_l2<128><<<dim3(8, 256), 256, 0, stream>>>(ll2, 128, h0a, h0b, h1a, h1b, ll3, yh3);
}

// Round 3
// 180.056 us; speedup vs baseline: 1.4339x; 1.4339x over previous
//
#include <hip/hip_runtime.h>

// DTCWT forward, J=3, B=4 C=64 H=W=256, fp32.
// XLA conv = cross-correlation (no flip). Reflection: half-sample symmetric.
// Level 2+: output pair u, even col/row: sum_k In[refl(4u+2k-8)]*h0b[k] (lo)
//           odd: refl(4u+2k-7)*h0a[k]; highpass swaps phases (h1a@odd->even out).
// All tap loops are branch-free; reflection is applied once during LDS staging
// via de-interleaved even/odd column arrays with halo.

#define NIMG 256
#define INV_SQRT2 0.7071067811865476f

__device__ __forceinline__ int refl(int i, int n) {
    return i < 0 ? (-i - 1) : (i >= n ? (2 * n - 1 - i) : i);
}

// ---------------- Level 1 ----------------
__global__ __launch_bounds__(256, 2)
void dtcwt_l1(const float* __restrict__ x,
              const float* __restrict__ h0o,
              const float* __restrict__ h1o,
              float* __restrict__ ll,     // (NIMG,256,256) ws
              float* __restrict__ yh)     // (NIMG,6,128,128,2)
{
    __shared__ float xs [22][262];   // col c at [c+3], c in [-3,258], pre-reflected
    __shared__ float slo[22][258];
    __shared__ float shi[22][258];

    const int img = blockIdx.y;
    const int r0  = blockIdx.x * 16;
    const int tid = threadIdx.x;

    float f0[5], f1[7];
#pragma unroll
    for (int k = 0; k < 5; ++k) f0[k] = h0o[k];
#pragma unroll
    for (int k = 0; k < 7; ++k) f1[k] = h1o[k];

    const float* xim = x + (size_t)img * 65536;

    // stage 22 rows (row-reflected), main cols via float2
    for (int idx = tid; idx < 22 * 128; idx += 256) {
        int lr = idx >> 7, cp = idx & 127;
        int gr = refl(r0 - 3 + lr, 256);
        float2 v = *(const float2*)(xim + gr * 256 + 2 * cp);
        xs[lr][2 * cp + 3] = v.x;
        xs[lr][2 * cp + 4] = v.y;
    }
    // col halos: c in {-3,-2,-1,256,257,258}
    if (tid < 132) {
        int lr = tid / 6, h = tid % 6;
        int gr = refl(r0 - 3 + lr, 256);
        int c = (h < 3) ? (h - 3) : (253 + h);
        xs[lr][c + 3] = xim[gr * 256 + refl(c, 256)];
    }
    __syncthreads();

    // row filter, 2 output cols per thread, branch-free, no refl
    for (int idx = tid; idx < 22 * 128; idx += 256) {
        int lr = idx >> 7, cp = idx & 127;
        const float* p = &xs[lr][2 * cp];       // s[t] = X[refl(2cp - 3 + t)]
        float2 q0 = *(const float2*)(p + 0);
        float2 q1 = *(const float2*)(p + 2);
        float2 q2 = *(const float2*)(p + 4);
        float2 q3 = *(const float2*)(p + 6);
        float s[8] = {q0.x, q0.y, q1.x, q1.y, q2.x, q2.y, q3.x, q3.y};
        float alo0 = 0.f, alo1 = 0.f, ahi0 = 0.f, ahi1 = 0.f;
#pragma unroll
        for (int k = 0; k < 5; ++k) {
            alo0 = fmaf(f0[k], s[k + 1], alo0);
            alo1 = fmaf(f0[k], s[k + 2], alo1);
        }
#pragma unroll
        for (int k = 0; k < 7; ++k) {
            ahi0 = fmaf(f1[k], s[k], ahi0);
            ahi1 = fmaf(f1[k], s[k + 1], ahi1);
        }
        *(float2*)&slo[lr][2 * cp] = make_float2(alo0, alo1);
        *(float2*)&shi[lr][2 * cp] = make_float2(ahi0, ahi1);
    }
    __syncthreads();

    // fused col filter + q2c: one thread per 2x2 output quad
    float* llim = ll + (size_t)img * 65536;
    float* yim  = yh + (size_t)img * (6 * 128 * 128 * 2);
    for (int idx = tid; idx < 8 * 128; idx += 256) {
        int ii = idx >> 7, j = idx & 127;       // out rows 2ii,2ii+1 cols 2j,2j+1
        float2 lo2[8], hi2[8];
#pragma unroll
        for (int t = 0; t < 8; ++t) {
            lo2[t] = *(const float2*)&slo[2 * ii + t][2 * j];
            hi2[t] = *(const float2*)&shi[2 * ii + t][2 * j];
        }
        float ll00=0,ll01=0,ll10=0,ll11=0, lh00=0,lh01=0,lh10=0,lh11=0;
        float hl00=0,hl01=0,hl10=0,hl11=0, hh00=0,hh01=0,hh10=0,hh11=0;
#pragma unroll
        for (int k = 0; k < 5; ++k) {
            float fk = f0[k];
            ll00 = fmaf(fk, lo2[k + 1].x, ll00); ll01 = fmaf(fk, lo2[k + 1].y, ll01);
            ll10 = fmaf(fk, lo2[k + 2].x, ll10); ll11 = fmaf(fk, lo2[k + 2].y, ll11);
            hl00 = fmaf(fk, hi2[k + 1].x, hl00); hl01 = fmaf(fk, hi2[k + 1].y, hl01);
            hl10 = fmaf(fk, hi2[k + 2].x, hl10); hl11 = fmaf(fk, hi2[k + 2].y, hl11);
        }
#pragma unroll
        for (int k = 0; k < 7; ++k) {
            float fk = f1[k];
            lh00 = fmaf(fk, lo2[k].x, lh00);     lh01 = fmaf(fk, lo2[k].y, lh01);
            lh10 = fmaf(fk, lo2[k + 1].x, lh10); lh11 = fmaf(fk, lo2[k + 1].y, lh11);
            hh00 = fmaf(fk, hi2[k].x, hh00);     hh01 = fmaf(fk, hi2[k].y, hh01);
            hh10 = fmaf(fk, hi2[k + 1].x, hh10); hh11 = fmaf(fk, hi2[k + 1].y, hh11);
        }
        int orow = r0 + 2 * ii;
        *(float2*)(llim + (size_t)orow * 256 + 2 * j)       = make_float2(ll00, ll01);
        *(float2*)(llim + (size_t)(orow + 1) * 256 + 2 * j) = make_float2(ll10, ll11);
        const int i = (r0 >> 1) + ii;
        const float sc = INV_SQRT2;
        float a, b, c, d;
        a = lh00 * sc; b = lh01 * sc; c = lh10 * sc; d = lh11 * sc;
        *(float2*)(yim + ((size_t)(0 * 128 + i) * 128 + j) * 2) = make_float2(a - d, b + c);
        *(float2*)(yim + ((size_t)(5 * 128 + i) * 128 + j) * 2) = make_float2(a + d, b - c);
        a = hh00 * sc; b = hh01 * sc; c = hh10 * sc; d = hh11 * sc;
        *(float2*)(yim + ((size_t)(1 * 128 + i) * 128 + j) * 2) = make_float2(a - d, b + c);
        *(float2*)(yim + ((size_t)(4 * 128 + i) * 128 + j) * 2) = make_float2(a + d, b - c);
        a = hl00 * sc; b = hl01 * sc; c = hl10 * sc; d = hl11 * sc;
        *(float2*)(yim + ((size_t)(2 * 128 + i) * 128 + j) * 2) = make_float2(a - d, b + c);
        *(float2*)(yim + ((size_t)(3 * 128 + i) * 128 + j) * 2) = make_float2(a + d, b - c);
    }
}

// ---------------- Levels 2+ ----------------
template <int CI, int NI>
__global__ __launch_bounds__(256, 2)
void dtcwt_l2(const float* __restrict__ llin,
              const float* __restrict__ h0a, const float* __restrict__ h0b,
              const float* __restrict__ h1a, const float* __restrict__ h1b,
              float* __restrict__ llout,   // (NIMG, CI/2, CI/2)
              float* __restrict__ yh)      // (NIMG, 6, CI/4, CI/4, 2)
{
    constexpr int CH2 = CI / 2;
    constexpr int CQ  = CI / 4;
    constexpr int Nj  = CI / 4;          // rowdfilt output pairs per row
    constexpr int NR  = 4 * NI + 16;     // staged rows [4*i0-8, 4*i0+4*NI+7]
    constexpr int LDE = CI / 2 + 9;      // odd row stride, entries m in [-4, CI/2+3] at [m+4]
    constexpr int LDY = Nj + 1;          // odd

    __shared__ float xsE [NR][LDE], xsO [NR][LDE];
    __shared__ float yloE[NR][LDY], yloO[NR][LDY];
    __shared__ float yhiE[NR][LDY], yhiO[NR][LDY];

    const int img = blockIdx.y;
    const int i0  = blockIdx.x * NI;
    const int tid = threadIdx.x;

    float fa0[10], fb0[10], fa1[10], fb1[10];
#pragma unroll
    for (int k = 0; k < 10; ++k) {
        fa0[k] = h0a[k]; fb0[k] = h0b[k];
        fa1[k] = h1a[k]; fb1[k] = h1b[k];
    }

    const float* xim = llin + (size_t)img * CI * CI;

    // stage, de-interleaved: xsE[r][m+4] = X[r][refl(2m)], xsO: refl(2m+1)
    for (int idx = tid; idx < NR * (CI / 2); idx += 256) {
        int lr = idx / (CI / 2), cp = idx % (CI / 2);
        int gr = refl(4 * i0 - 8 + lr, CI);
        float2 v = *(const float2*)(xim + (size_t)gr * CI + 2 * cp);
        xsE[lr][cp + 4] = v.x;
        xsO[lr][cp + 4] = v.y;
    }
    for (int idx = tid; idx < NR * 8; idx += 256) {   // halo m in {-4..-1, CI/2..CI/2+3}
        int lr = idx >> 3, h = idx & 7;
        int gr = refl(4 * i0 - 8 + lr, CI);
        int m = (h < 4) ? (h - 4) : (CI / 2 + h - 4);
        xsE[lr][m + 4] = xim[(size_t)gr * CI + refl(2 * m, CI)];
        xsO[lr][m + 4] = xim[(size_t)gr * CI + refl(2 * m + 1, CI)];
    }
    __syncthreads();

    // rowdfilt: thread computes both phases of both trees at (r, j)
    for (int idx = tid; idx < NR * Nj; idx += 256) {
        int r = idx % NR, j = idx / NR;
        const float* pE = &xsE[r][2 * j];    // pE[k] = X[refl(4j+2k-8)]
        const float* pO = &xsO[r][2 * j];    // pO[k] = X[refl(4j+2k-7)]
        float vloE = 0.f, vloO = 0.f, vhiE = 0.f, vhiO = 0.f;
#pragma unroll
        for (int k = 0; k < 10; ++k) {
            float xa = pE[k], xb = pO[k];
            vloE = fmaf(xa, fb0[k], vloE);
            vloO = fmaf(xb, fa0[k], vloO);
            vhiE = fmaf(xb, fa1[k], vhiE);
            vhiO = fmaf(xa, fb1[k], vhiO);
        }
        yloE[r][j] = vloE; yloO[r][j] = vloO;
        yhiE[r][j] = vhiE; yhiO[r][j] = vhiO;
    }
    __syncthreads();

    // coldfilt + in-register q2c: thread per (ii, j) 2x2 quad, all 4 bands
    float* llo = llout + (size_t)img * CH2 * CH2;
    float* yim = yh + (size_t)img * (6 * CQ * CQ * 2);
    for (int idx = tid; idx < NI * CQ; idx += 256) {
        int ii = idx / CQ, j = idx % CQ;
        float ll00=0,ll01=0,ll10=0,ll11=0, lh00=0,lh01=0,lh10=0,lh11=0;
        float hl00=0,hl01=0,hl10=0,hl11=0, hh00=0,hh01=0,hh10=0,hh11=0;
#pragma unroll
        for (int k = 0; k < 10; ++k) {
            int ra = 4 * ii + 2 * k, rb = ra + 1;
            float lAx = yloE[ra][j], lAy = yloO[ra][j];
            float lBx = yloE[rb][j], lBy = yloO[rb][j];
            float hAx = yhiE[ra][j], hAy = yhiO[ra][j];
            float hBx = yhiE[rb][j], hBy = yhiO[rb][j];
            float a0 = fa0[k], b0 = fb0[k], a1 = fa1[k], b1 = fb1[k];
            ll00 = fmaf(lAx, b0, ll00); ll01 = fmaf(lAy, b0, ll01);
            ll10 = fmaf(lBx, a0, ll10); ll11 = fmaf(lBy, a0, ll11);
            lh00 = fmaf(lBx, a1, lh00); lh01 = fmaf(lBy, a1, lh01);
            lh10 = fmaf(lAx, b1, lh10); lh11 = fmaf(lAy, b1, lh11);
            hl00 = fmaf(hAx, b0, hl00); hl01 = fmaf(hAy, b0, hl01);
            hl10 = fmaf(hBx, a0, hl10); hl11 = fmaf(hBy, a0, hl11);
            hh00 = fmaf(hBx, a1, hh00); hh01 = fmaf(hBy, a1, hh01);
            hh10 = fmaf(hAx, b1, hh10); hh11 = fmaf(hAy, b1, hh11);
        }
        int orow = 2 * (i0 + ii);
        *(float2*)(llo + (size_t)orow * CH2 + 2 * j)       = make_float2(ll00, ll01);
        *(float2*)(llo + (size_t)(orow + 1) * CH2 + 2 * j) = make_float2(ll10, ll11);
        const int i = i0 + ii;
        const float sc = INV_SQRT2;
        float a, b, c, d;
        a = lh00 * sc; b = lh01 * sc; c = lh10 * sc; d = lh11 * sc;
        *(float2*)(yim + ((size_t)(0 * CQ + i) * CQ + j) * 2) = make_float2(a - d, b + c);
        *(float2*)(yim + ((size_t)(5 * CQ + i) * CQ + j) * 2) = make_float2(a + d, b - c);
        a = hh00 * sc; b = hh01 * sc; c = hh10 * sc; d = hh11 * sc;
        *(float2*)(yim + ((size_t)(1 * CQ + i) * CQ + j) * 2) = make_float2(a - d, b + c);
        *(float2*)(yim + ((size_t)(4 * CQ + i) * CQ + j) * 2) = make_float2(a + d, b - c);
        a = hl00 * sc; b = hl01 * sc; c = hl10 * sc; d = hl11 * sc;
        *(float2*)(yim + ((size_t)(2 * CQ + i) * CQ + j) * 2) = make_float2(a - d, b + c);
        *(float2*)(yim + ((size_t)(3 * CQ + i) * CQ + j) * 2) = make_float2(a + d, b - c);
    }
}

extern "C" void kernel_launch(void* const* d_in, const int* in_sizes, int n_in,
                              void* d_out, int out_size, void* d_ws, size_t ws_size,
                              hipStream_t stream)
{
    const float* x   = (const float*)d_in[0];
    const float* h0o = (const float*)d_in[1];
    const float* h1o = (const float*)d_in[2];
    const float* h0a = (const float*)d_in[3];
    const float* h0b = (const float*)d_in[4];
    const float* h1a = (const float*)d_in[5];
    const float* h1b = (const float*)d_in[6];
    float* out = (float*)d_out;

    float* ll1 = (float*)d_ws;            // 16,777,216 floats (64 MB)
    float* ll2 = ll1 + 16777216;          //  4,194,304 floats (16 MB)

    float* ll3 = out;                     //  1,048,576
    float* yh1 = out + 1048576;           // 50,331,648
    float* yh2 = out + 51380224;          // 12,582,912
    float* yh3 = out + 63963136;          //  3,145,728

    dtcwt_l1<<<dim3(16, 256), 256, 0, stream>>>(x, h0o, h1o, ll1, yh1);
    dtcwt_l2<256, 4><<<dim3(16, 256), 256, 0, stream>>>(ll1, h0a, h0b, h1a, h1b, ll2, yh2);
    dtcwt_l2<128, 8><<<dim3(4, 256), 256, 0, stream>>>(ll2, h0a, h0b, h1a, h1b, ll3, yh3);
}